// Round 2
// baseline (415.030 us; speedup 1.0000x reference)
//
#include <hip/hip_runtime.h>
#include <hip/hip_cooperative_groups.h>
#include <math.h>

namespace cg = cooperative_groups;

#define BS 256
#define GTMAX 64
#define KMAX 1024
#define CH_MAX 480
#define MS 28
#define MSQ (MS*MS)

// Pinned-op IoU: bit-identical wherever inlined (force_pos float equality).
__device__ __forceinline__ float box_area(float4 b) {
    return __fmul_rn(__fsub_rn(b.z, b.x), __fsub_rn(b.w, b.y));
}
__device__ __forceinline__ float iou_f(float4 a, float areaA, float4 b, float areaB) {
    float lx = fmaxf(a.x, b.x), ly = fmaxf(a.y, b.y);
    float rx = fminf(a.z, b.z), ry = fminf(a.w, b.w);
    float w = fmaxf(__fsub_rn(rx, lx), 0.0f);
    float h = fmaxf(__fsub_rn(ry, ly), 0.0f);
    float inter = __fmul_rn(w, h);
    float den = __fsub_rn(__fadd_rn(areaA, areaB), inter);
    return __fdividef(inter, den);
}
__device__ __forceinline__ float sl1(float x) {
    float ax = fabsf(x);
    return ax < 1.0f ? 0.5f * ax * ax : ax - 0.5f;
}
__device__ __forceinline__ float bce(float l, float t) {
    return fmaxf(l, 0.0f) - l * t + log1pf(expf(-fabsf(l)));
}

struct ShA { float4 abox[CH_MAX]; float aarea[CH_MAX]; };                  // 9600 B
struct ShD { float miou[KMAX]; int gi[KMAX]; short pl[KMAX]; };           // 10240 B

// acc: 0 rpn_ce, 1 rpn_valid, 2 rpn_reg, 3 rpn_pos, 4 det_ce, 5 det_sel,
//      6 det_reg, 7 det_selfg, 8 vis_sum, 9 amo_sum, 10 keep_cnt
__global__ __launch_bounds__(BS, 4) void k_fused(
    const float2* __restrict__ rpn_cls, const float4* __restrict__ rpn_pred,
    const float4* __restrict__ anchors, const float4* __restrict__ gt,
    const int* __restrict__ gt_labels, const float* __restrict__ roi_cls,
    const float* __restrict__ roi_deltas, const float4* __restrict__ proposals,
    const float* __restrict__ mvl, const float* __restrict__ mal,
    const float* __restrict__ vism, const float* __restrict__ amom,
    int N, int M, int K, int C, int H, int CHUNK, int NB,
    float* acc, float* gmaxf, float* bmaxT, int* pinfo, float* out)
{
    cg::grid_group grid = cg::this_grid();
    __shared__ __align__(16) char shbuf[sizeof(ShD) > sizeof(ShA) ? sizeof(ShD) : sizeof(ShA)];
    __shared__ float4 sgt[GTMAX];
    __shared__ float sarea[GTMAX];
    __shared__ int   slab[GTMAX];
    __shared__ float smaxpg[GTMAX];
    __shared__ float sacc[4];
    __shared__ float sredM[4], sredE[4], sredV[4], sredA[4];
    __shared__ int   swtot[4];
    ShA* SA = (ShA*)shbuf;
    ShD* SD = (ShD*)shbuf;

    const int b = blockIdx.x, t = threadIdx.x;
    const int wave = t >> 6, lane = t & 63;

    if (t < M) {
        float4 g = gt[t];
        sgt[t] = g; sarea[t] = box_area(g); slab[t] = gt_labels[t];
    }
    if (b == 0 && t < 16) acc[t] = 0.0f;

    // ================= Phase A: per-block per-gt max IoU =================
    // Each wave owns 16 gt's; running maxima in registers; anchors staged in LDS.
    {
        int base = b * CHUNK;
        int cnt = min(CHUNK, N - base);           // may be <= 0 for tail blocks
        float mj[16];
        #pragma unroll
        for (int jj = 0; jj < 16; ++jj) mj[jj] = -INFINITY;
        for (int tile = 0; tile < cnt; tile += CH_MAX) {
            int tcnt = min(CH_MAX, cnt - tile);
            __syncthreads();
            for (int k = t; k < tcnt; k += BS) {
                float4 a = anchors[base + tile + k];
                SA->abox[k] = a;
                SA->aarea[k] = box_area(a);
            }
            __syncthreads();
            for (int k = lane; k < tcnt; k += 64) {
                float4 a = SA->abox[k];
                float aa = SA->aarea[k];
                #pragma unroll
                for (int jj = 0; jj < 16; ++jj) {
                    int j = wave * 16 + jj;
                    if (j < M) mj[jj] = fmaxf(mj[jj], iou_f(a, aa, sgt[j], sarea[j]));
                }
            }
        }
        #pragma unroll
        for (int jj = 0; jj < 16; ++jj) {
            float m = mj[jj];
            for (int off = 32; off; off >>= 1) m = fmaxf(m, __shfl_xor(m, off));
            int j = wave * 16 + jj;
            if (lane == 0 && j < GTMAX) bmaxT[(size_t)j * NB + b] = m;
        }
    }
    grid.sync();

    // ===== Phase A2: blocks 0..63 reduce per-gt max; block 64 det head =====
    if (b < GTMAX) {
        float m = -INFINITY;
        if (b < M)
            for (int i = t; i < NB; i += BS) m = fmaxf(m, bmaxT[(size_t)b * NB + i]);
        for (int off = 32; off; off >>= 1) m = fmaxf(m, __shfl_xor(m, off));
        if (lane == 0) sredM[wave] = m;
        __syncthreads();
        if (t == 0) gmaxf[b] = fmaxf(fmaxf(sredM[0], sredM[1]), fmaxf(sredM[2], sredM[3]));
    } else if (b == GTMAX) {
        // --- matching ---
        for (int p = t; p < K; p += BS) {
            float4 a = proposals[p];
            float areaA = box_area(a);
            float mx = -1.0f; int am = 0;
            for (int j = 0; j < M; ++j) {
                float v = iou_f(a, areaA, sgt[j], sarea[j]);
                if (v > mx) { mx = v; am = j; }
            }
            SD->miou[p] = mx; SD->gi[p] = am;
            int pl = slab[am];
            if (mx < 0.5f) pl = 0;
            if (mx < 0.1f) pl = -1;
            SD->pl[p] = (short)pl;
        }
        __syncthreads();
        // --- parallel fg/bg cumsum selection (4 contiguous p per thread) ---
        int myp0 = t * 4;
        int cf = 0, cb = 0;
        for (int e = 0; e < 4; ++e) {
            int p = myp0 + e;
            if (p < K) { int pl = SD->pl[p]; cf += (pl > 0); cb += (pl == 0); }
        }
        int packed = cf | (cb << 16);
        int scan = packed;
        for (int off = 1; off < 64; off <<= 1) {
            int n = __shfl_up(scan, off);
            if (lane >= off) scan += n;
        }
        if (lane == 63) swtot[wave] = scan;
        __syncthreads();
        int woff = 0, tot = 0;
        for (int w = 0; w < 4; ++w) { int v = swtot[w]; if (w < wave) woff += v; tot += v; }
        int excl = scan - packed + woff;
        int runf = excl & 0xffff, runb = (excl >> 16) & 0xffff;
        int totfg = tot & 0xffff, totbg = (tot >> 16) & 0xffff;
        int nfg = totfg < 32 ? totfg : 32;
        int nbg = 128 - nfg;
        int keeploc = 0;
        for (int e = 0; e < 4; ++e) {
            int p = myp0 + e;
            if (p < K) {
                int pl = SD->pl[p];
                int sf = 0, sb = 0;
                if (pl > 0)       { runf++; sf = (runf <= nfg); }
                else if (pl == 0) { runb++; sb = (runb <= nbg); }
                int kp = SD->miou[p] >= 0.5f ? 1 : 0;
                keeploc += kp;
                int lab = pl > 0 ? pl : 0;
                pinfo[p] = SD->gi[p] | (lab << 6) | (sf << 13) | (sb << 14) | (kp << 15);
            }
        }
        for (int off = 32; off; off >>= 1) keeploc += __shfl_xor(keeploc, off);
        if (lane == 0) sredM[wave] = (float)keeploc;
        __syncthreads();
        if (t == 0) {
            acc[7]  = (float)nfg;
            acc[5]  = (float)(nfg + (totbg < nbg ? totbg : nbg));
            acc[10] = sredM[0] + sredM[1] + sredM[2] + sredM[3];
        }
    }
    grid.sync();

    // ========== Phase BD: RPN losses (grid-stride) + det/mask (p = b) ==========
    if (t < GTMAX) smaxpg[t] = gmaxf[t];
    if (t < 4) sacc[t] = 0.0f;
    __syncthreads();

    {   // RPN
        float ce = 0.f, valid = 0.f, pos = 0.f, reg = 0.f;
        for (int i = b * BS + t; i < N; i += NB * BS) {
            float4 a = anchors[i];
            float areaA = box_area(a);
            float maxiou = -1.0f; int arg = 0; bool force = false;
            for (int j = 0; j < M; ++j) {
                float v = iou_f(a, areaA, sgt[j], sarea[j]);
                if (v > maxiou) { maxiou = v; arg = j; }
                force = force || (v == smaxpg[j]);
            }
            int label = force ? 1 : (maxiou >= 0.7f ? 1 : (maxiou <= 0.3f ? 0 : -1));
            if (label >= 0) {
                valid += 1.0f;
                float2 x = rpn_cls[i];
                float m = fmaxf(x.x, x.y);
                float lse = m + logf(expf(x.x - m) + expf(x.y - m));
                ce += -((label == 1 ? x.y : x.x) - lse);
            }
            if (label == 1) {
                pos += 1.0f;
                float4 g = sgt[arg];
                float rw = a.z - a.x, rh = a.w - a.y;
                float t0 = ((g.x + g.z) * 0.5f - (a.x + a.z) * 0.5f) / rw;
                float t1 = ((g.y + g.w) * 0.5f - (a.y + a.w) * 0.5f) / rh;
                float t2 = logf((g.z - g.x) / rw);
                float t3 = logf((g.w - g.y) / rh);
                float4 p = rpn_pred[i];
                reg += sl1(p.x - t0) + sl1(p.y - t1) + sl1(p.z - t2) + sl1(p.w - t3);
            }
        }
        for (int off = 32; off; off >>= 1) {
            ce += __shfl_xor(ce, off); valid += __shfl_xor(valid, off);
            pos += __shfl_xor(pos, off); reg += __shfl_xor(reg, off);
        }
        if (lane == 0) {
            atomicAdd(&sacc[0], ce); atomicAdd(&sacc[1], valid);
            atomicAdd(&sacc[2], reg); atomicAdd(&sacc[3], pos);
        }
        __syncthreads();
        if (t == 0) {
            atomicAdd(&acc[0], sacc[0]); atomicAdd(&acc[1], sacc[1]);
            atomicAdd(&acc[2], sacc[2]); atomicAdd(&acc[3], sacc[3]);
        }
    }

    if (b < K) {   // det CE/reg + mask for proposal p = b
        int info = pinfo[b];
        int gi = info & 63, lab = (info >> 6) & 0x7f;
        bool sf = (info >> 13) & 1, sb = (info >> 14) & 1, kp = (info >> 15) & 1;
        if (sf || sb) {
            const float* row = roi_cls + (size_t)b * C;
            float v = (t < C) ? row[t] : -INFINITY;
            float m = v;
            for (int off = 32; off; off >>= 1) m = fmaxf(m, __shfl_xor(m, off));
            if (lane == 0) sredM[wave] = m;
            __syncthreads();
            m = fmaxf(fmaxf(sredM[0], sredM[1]), fmaxf(sredM[2], sredM[3]));
            float e = (t < C) ? expf(v - m) : 0.0f;
            for (int off = 32; off; off >>= 1) e += __shfl_xor(e, off);
            if (lane == 0) sredE[wave] = e;
            __syncthreads();
            if (t == 0) {
                float lse = m + logf(sredE[0] + sredE[1] + sredE[2] + sredE[3]);
                atomicAdd(&acc[4], -(row[lab] - lse));
            }
        }
        if (sf && t == 0) {
            float4 a = proposals[b];
            float4 g = sgt[gi];
            float rw = a.z - a.x, rh = a.w - a.y;
            float t0 = ((g.x + g.z) * 0.5f - (a.x + a.z) * 0.5f) / rw;
            float t1 = ((g.y + g.w) * 0.5f - (a.y + a.w) * 0.5f) / rh;
            float t2 = logf((g.z - g.x) / rw);
            float t3 = logf((g.w - g.y) / rh);
            const float* pr = roi_deltas + ((size_t)b * C + lab) * 4;
            float r = sl1(pr[0] - t0) + sl1(pr[1] - t1) + sl1(pr[2] - t2) + sl1(pr[3] - t3);
            atomicAdd(&acc[6], r);
        }
        if (kp) {
            int mlab = slab[gi];
            float4 r = proposals[b];
            float x1 = r.x - 0.5f, y1 = r.y - 0.5f;
            float bw = (r.z - r.x) / (float)MS;
            float bh = (r.w - r.y) / (float)MS;
            const float* vm = vism + (size_t)gi * H * H;
            const float* am = amom + (size_t)gi * H * H;
            const float* lv = mvl + ((size_t)b * C + mlab) * MSQ;
            const float* la = mal + ((size_t)b * C + mlab) * MSQ;
            float sv = 0.f, sa = 0.f;
            for (int px = t; px < MSQ; px += BS) {
                int gx = px % MS, gy = px / MS;
                float X = x1 + ((float)gx + 0.5f) * bw;
                float Y = y1 + ((float)gy + 0.5f) * bh;
                bool valid = (Y > -1.0f) && (Y < (float)H) && (X > -1.0f) && (X < (float)H);
                float Yc = fminf(fmaxf(Y, 0.0f), (float)(H - 1));
                float Xc = fminf(fmaxf(X, 0.0f), (float)(H - 1));
                int y0 = (int)floorf(Yc), x0 = (int)floorf(Xc);
                int y1i = min(y0 + 1, H - 1), x1i = min(x0 + 1, H - 1);
                float ly = Yc - (float)y0, lx = Xc - (float)x0;
                float w00 = (1.f - ly) * (1.f - lx), w01 = (1.f - ly) * lx;
                float w10 = ly * (1.f - lx), w11 = ly * lx;
                float tv = vm[y0 * H + x0] * w00 + vm[y0 * H + x1i] * w01 +
                           vm[y1i * H + x0] * w10 + vm[y1i * H + x1i] * w11;
                float ta = am[y0 * H + x0] * w00 + am[y0 * H + x1i] * w01 +
                           am[y1i * H + x0] * w10 + am[y1i * H + x1i] * w11;
                if (!valid) { tv = 0.f; ta = 0.f; }
                sv += bce(lv[px], tv);
                sa += bce(la[px], ta);
            }
            for (int off = 32; off; off >>= 1) {
                sv += __shfl_xor(sv, off);
                sa += __shfl_xor(sa, off);
            }
            if (lane == 0) { sredV[wave] = sv; sredA[wave] = sa; }
            __syncthreads();
            if (t == 0) {
                atomicAdd(&acc[8], sredV[0] + sredV[1] + sredV[2] + sredV[3]);
                atomicAdd(&acc[9], sredA[0] + sredA[1] + sredA[2] + sredA[3]);
            }
        }
    }
    grid.sync();

    // ================= Finalize =================
    if (b == 0 && t == 0) {
        float rpn_cls_l = acc[0] / fmaxf(acc[1], 1.0f);
        float rpn_reg_l = acc[2] / fmaxf(acc[3] * 4.0f, 1.0f);
        float det_cls_l = acc[4] / fmaxf(acc[5], 1.0f);
        float det_reg_l = acc[6] / fmaxf(acc[7] * 4.0f, 1.0f);
        float den = fmaxf(acc[10], 1.0f) * (float)MSQ;
        out[0] = rpn_cls_l + rpn_reg_l + det_cls_l + det_reg_l + acc[8] / den + acc[9] / den;
    }
}

extern "C" void kernel_launch(void* const* d_in, const int* in_sizes, int n_in,
                              void* d_out, int out_size, void* d_ws, size_t ws_size,
                              hipStream_t stream) {
    const float2* rpn_cls   = (const float2*)d_in[0];
    const float4* rpn_pred  = (const float4*)d_in[1];
    const float4* anchors   = (const float4*)d_in[2];
    const float4* gt        = (const float4*)d_in[3];
    const int*    gt_labels = (const int*)d_in[4];
    const float*  roi_cls   = (const float*)d_in[5];
    const float*  roi_deltas= (const float*)d_in[6];
    const float4* proposals = (const float4*)d_in[7];
    const float*  mvl       = (const float*)d_in[8];
    const float*  mal       = (const float*)d_in[9];
    const float*  vism      = (const float*)d_in[10];
    const float*  amom      = (const float*)d_in[11];

    int N = in_sizes[0] / 2;
    int M = in_sizes[3] / 4;
    int K = in_sizes[7] / 4;
    int C = in_sizes[5] / K;
    int HW = in_sizes[10] / M;
    int H = (int)(sqrt((double)HW) + 0.5);

    // Cooperative grid sizing: <= resident capacity (host code runs once at capture).
    int NB = 1024;
    int maxblk = 0;
    if (hipOccupancyMaxActiveBlocksPerMultiprocessor(&maxblk, (const void*)k_fused, BS, 0) == hipSuccess
        && maxblk > 0) {
        int dev = 0;
        hipGetDevice(&dev);
        int cus = 0;
        if (hipDeviceGetAttribute(&cus, hipDeviceAttributeMultiprocessorCount, dev) == hipSuccess
            && cus > 0) {
            int cap = maxblk * cus;
            if (cap < NB) NB = cap;
        }
    }
    if (NB > 1024) NB = 1024;
    if (NB < 66) NB = 66;                    // blocks 0..64 have roles in phase A2
    int CHUNK = (N + NB - 1) / NB;

    float* wsf    = (float*)d_ws;
    float* acc    = wsf;                     // 16
    float* gmaxf  = wsf + 16;                // 64
    float* bmaxT  = wsf + 80;                // 64*1024 max
    int*   pinfo  = (int*)(wsf + 80 + 64 * 1024);   // K
    float* out    = (float*)d_out;

    void* args[] = { (void*)&rpn_cls, (void*)&rpn_pred, (void*)&anchors, (void*)&gt,
                     (void*)&gt_labels, (void*)&roi_cls, (void*)&roi_deltas, (void*)&proposals,
                     (void*)&mvl, (void*)&mal, (void*)&vism, (void*)&amom,
                     (void*)&N, (void*)&M, (void*)&K, (void*)&C, (void*)&H,
                     (void*)&CHUNK, (void*)&NB,
                     (void*)&acc, (void*)&gmaxf, (void*)&bmaxT, (void*)&pinfo, (void*)&out };
    hipLaunchCooperativeKernel((void*)k_fused, dim3(NB), dim3(BS), args, 0, stream);
}